// Round 9
// baseline (64.431 us; speedup 1.0000x reference)
//
#include <hip/hip_runtime.h>

// ---- lane-exchange primitives ----
template<int CTRL>
__device__ __forceinline__ float dpp1(float v) {
    return __int_as_float(__builtin_amdgcn_update_dpp(
        0, __float_as_int(v), CTRL, 0xF, 0xF, true));
}
#define QP_XOR1   0xB1   // quad_perm [1,0,3,2]
#define QP_XOR2   0x4E   // quad_perm [2,3,0,1]
#define QP_XOR3   0x1B   // quad_perm [3,2,1,0]
#define ROW_ROR8  0x128

template<int MASK>
__device__ __forceinline__ float swz(float v) {
    return __int_as_float(__builtin_amdgcn_ds_swizzle(
        __float_as_int(v), (MASK << 10) | 0x1F));
}

// exact xor-MASK exchange within 32-lane halves: DPP intra-quad, DS swizzle >=4
template<int MASK>
__device__ __forceinline__ float XL(float v) {
    if constexpr (MASK == 1)       return dpp1<QP_XOR1>(v);
    else if constexpr (MASK == 2)  return dpp1<QP_XOR2>(v);
    else if constexpr (MASK == 3)  return dpp1<QP_XOR3>(v);
    else                           return swz<MASK>(v);   // 4,6,8,12,16,24
}

__device__ __forceinline__ float xorf(float v, unsigned s) {
    return __int_as_float(__float_as_int(v) ^ (int)s);
}

// ---- cross-lane 2x2 gate on 8 amps, partner = lane ^ MASK ----
template<int MASK>
__device__ __forceinline__ void lane_gate(float (&re)[8], float (&im)[8],
                                          float car, float cai, float cbr, float cbi) {
#pragma unroll
    for (int r = 0; r < 8; ++r) {
        const float ar = re[r], ai = im[r];
        const float br = XL<MASK>(ar), bi = XL<MASK>(ai);
        re[r] = car * ar - cai * ai + cbr * br - cbi * bi;
        im[r] = car * ai + cai * ar + cbr * bi + cbi * br;
    }
}

// ---- in-register 2x2 gate: pairs (r, r^MASK); element-hi = parity(r & FBITS)
// conj structure: u11 = conj(u00), u10 = -conj(u01).
template<int MASK, int FBITS>
__device__ __forceinline__ void reg_gate(float (&re)[8], float (&im)[8],
        float cr, float ci, float dr, float di) {
    constexpr int MSB = (MASK & 4) ? 4 : (MASK & 2) ? 2 : 1;
#pragma unroll
    for (int r = 0; r < 8; ++r) {
        if (r & MSB) continue;
        const int p = r ^ MASK;
        const bool f = __builtin_popcount(r & FBITS) & 1;  // compile-time
        const float sAi = f ? -ci : ci;   // folds into FMA input modifier
        const float tAr = f ? -dr : dr;
        const float ar = re[r], ai = im[r], br = re[p], bi = im[p];
        re[r] = cr * ar - sAi * ai + tAr * br - di * bi;
        im[r] = cr * ai + sAi * ar + tAr * bi + di * br;
        re[p] = cr * br + sAi * bi - tAr * ar - di * ai;
        im[p] = cr * bi - sAi * br - tAr * ai + di * ar;
    }
}

__global__ __launch_bounds__(256, 8) void quantum_kernel(
    const float* __restrict__ x,
    const float* __restrict__ theta,
    float* __restrict__ out,
    int B)
{
    // ---- per-block: 16 gate rows (u00r,u00i,u01r,u01i) in LDS ----
    __shared__ float4 g4[16];
    const int t = threadIdx.x;
    if (t < 16) {
        const int layer = t >> 3, q = t & 7;
        const float phi = theta[(layer * 8 + q) * 3 + 0];
        const float th  = theta[(layer * 8 + q) * 3 + 1];
        const float om  = theta[(layer * 8 + q) * 3 + 2];
        const float ct = __cosf(0.5f * th), st = __sinf(0.5f * th);
        const float a = 0.5f * (phi + om), b = 0.5f * (phi - om);
        const float ca = __cosf(a), sa = __sinf(a);
        const float cb = __cosf(b), sb = __sinf(b);
        g4[t] = make_float4(ct * ca, -ct * sa, -st * cb, -st * sb);
    }
    __syncthreads();

    const int tid = blockIdx.x * 256 + t;
    const int sample = tid >> 5;       // 32 lanes per sample
    if (sample >= B) return;
    const int sub = t & 31;            // lane bits b4..b0 <-> qubits 0..4

    // per-lane hi-parity sign words (prefix parities of physical bits p0..p4)
    const int y1 = sub ^ (sub >> 1);
    const int y2 = y1 ^ (sub >> 2);
    const int y3 = y2 ^ (sub >> 3);
    const int y4 = y3 ^ (sub >> 4);
    const unsigned s_q8  = (unsigned)(sub & 16) << 27;  // b4
    const unsigned s_q9  = (unsigned)(y1 & 8)  << 28;   // b4^b3
    const unsigned s_q10 = (unsigned)(y2 & 4)  << 29;   // b4^b3^b2
    const unsigned s_q11 = (unsigned)(y3 & 2)  << 30;   // b4^b3^b2^b1
    const unsigned s_par = (unsigned)(y4 & 1)  << 31;   // par5

    // ---- FUSED: encoding RY + ALL of layer-1 Rot -> complex product state ----
    float re[8], im[8];
    {
        const float4* xp = reinterpret_cast<const float4*>(x + sample * 8);
        const float4 xa = xp[0], xb = xp[1];
        const float xs[8] = {xa.x, xa.y, xa.z, xa.w, xb.x, xb.y, xb.z, xb.w};
        float cq[8], sq[8];
#pragma unroll
        for (int q = 0; q < 8; ++q) {
            // hardware sin/cos take REVOLUTIONS: 0.25 rev = pi/2 rad
            const float v = 0.25f * fminf(fmaxf(xs[q], -1.0f), 1.0f);
            cq[q] = __builtin_amdgcn_cosf(v);
            sq[q] = __builtin_amdgcn_sinf(v);
        }
        float wrr[5], wri[5];
        float v5r[2], v5i[2], v6r[2], v6i[2], v7r[2], v7i[2];
#pragma unroll
        for (int q = 0; q < 8; ++q) {
            const float4 gq = g4[q];
            const float c = cq[q], s = sq[q];
            const float v0r = gq.x * c + gq.z * s, v0i = gq.y * c + gq.w * s;
            const float v1r = gq.x * s - gq.z * c, v1i = gq.w * c - gq.y * s;
            if (q < 5) {
                const bool bit = (sub >> (4 - q)) & 1;
                wrr[q] = bit ? v1r : v0r;
                wri[q] = bit ? v1i : v0i;
            } else if (q == 5) {
                v5r[0] = v0r; v5i[0] = v0i; v5r[1] = v1r; v5i[1] = v1i;
            } else if (q == 6) {
                v6r[0] = v0r; v6i[0] = v0i; v6r[1] = v1r; v6i[1] = v1i;
            } else {
                v7r[0] = v0r; v7i[0] = v0i; v7r[1] = v1r; v7i[1] = v1i;
            }
        }
        // plane = ((w0*w1)*(w2*w3))*w4  (tree for shorter dep chain)
        float t01r = wrr[0] * wrr[1] - wri[0] * wri[1];
        float t01i = wrr[0] * wri[1] + wri[0] * wrr[1];
        float t23r = wrr[2] * wrr[3] - wri[2] * wri[3];
        float t23i = wrr[2] * wri[3] + wri[2] * wrr[3];
        float t03r = t01r * t23r - t01i * t23i;
        float t03i = t01r * t23i + t01i * t23r;
        const float pr  = t03r * wrr[4] - t03i * wri[4];
        const float pi_ = t03r * wri[4] + t03i * wrr[4];
        float p5r[2], p5i[2];
#pragma unroll
        for (int k = 0; k < 2; ++k) {
            p5r[k] = pr * v5r[k] - pi_ * v5i[k];
            p5i[k] = pr * v5i[k] + pi_ * v5r[k];
        }
        float h67r[4], h67i[4];
#pragma unroll
        for (int k = 0; k < 4; ++k) {
            h67r[k] = v6r[k >> 1] * v7r[k & 1] - v6i[k >> 1] * v7i[k & 1];
            h67i[k] = v6r[k >> 1] * v7i[k & 1] + v6i[k >> 1] * v7r[k & 1];
        }
#pragma unroll
        for (int r = 0; r < 8; ++r) {
            re[r] = p5r[r >> 2] * h67r[r & 3] - p5i[r >> 2] * h67i[r & 3];
            im[r] = p5r[r >> 2] * h67i[r & 3] + p5i[r >> 2] * h67r[r & 3];
        }
    }
    // layer-1 CNOT chain: GF(2) relabel -> zero instructions.

#define LOADG(idx) \
    const float4 gq = g4[idx]; \
    const float u00r = gq.x, u00i = gq.y, u01r = gq.z, u01i = gq.w;

#define LANE_SIGNED(sg) \
    const float car = u00r, cbi = u01i; \
    const float cai = xorf(u00i, sg), cbr = xorf(u01r, sg);

    // ================= LAYER 2 (M = prefix) =================
    { LOADG(8);  LANE_SIGNED(s_q8);  lane_gate<24>(re, im, car, cai, cbr, cbi); }
    { LOADG(9);  LANE_SIGNED(s_q9);  lane_gate<12>(re, im, car, cai, cbr, cbi); }
    { LOADG(10); LANE_SIGNED(s_q10); lane_gate<6>(re, im, car, cai, cbr, cbi); }
    { LOADG(11); LANE_SIGNED(s_q11); lane_gate<3>(re, im, car, cai, cbr, cbi); }
    // q4: partner = (lane^1, r^4); hi = par5 (uniform over regs)
    {
        LOADG(12); LANE_SIGNED(s_par);
#pragma unroll
        for (int r = 0; r < 4; ++r) {
            const float a0r = re[r],     a0i = im[r];
            const float a1r = re[r + 4], a1i = im[r + 4];
            const float p0r = dpp1<QP_XOR1>(a1r), p0i = dpp1<QP_XOR1>(a1i);
            const float p1r = dpp1<QP_XOR1>(a0r), p1i = dpp1<QP_XOR1>(a0i);
            re[r]     = car * a0r - cai * a0i + cbr * p0r - cbi * p0i;
            im[r]     = car * a0i + cai * a0r + cbr * p0i + cbi * p0r;
            re[r + 4] = car * a1r - cai * a1i + cbr * p1r - cbi * p1i;
            im[r + 4] = car * a1i + cai * a1r + cbr * p1i + cbi * p1r;
        }
    }
    // q5..q7: in-register; hi = par5 ^ parity(r & FBITS)
    { LOADG(13);
      const float ci2 = xorf(u00i, s_par), dr2 = xorf(u01r, s_par);
      reg_gate<6,4>(re, im, u00r, ci2, dr2, u01i); }
    { LOADG(14);
      const float ci2 = xorf(u00i, s_par), dr2 = xorf(u01r, s_par);
      reg_gate<3,6>(re, im, u00r, ci2, dr2, u01i); }
    { LOADG(15);
      const float ci2 = xorf(u00i, s_par), dr2 = xorf(u01r, s_par);
      reg_gate<1,7>(re, im, u00r, ci2, dr2, u01i); }

    // ================= measurement under final M =================
    // p0..p4 = lane bits b4..b0 ; p5,p6,p7 = reg bits r2,r1,r0
    float P[8];
#pragma unroll
    for (int r = 0; r < 8; ++r) P[r] = re[r] * re[r] + im[r] * im[r];

    const float t01 = P[0] + P[1], t23 = P[2] + P[3];
    const float t45 = P[4] + P[5], t67 = P[6] + P[7];
    const float ee = t01 + t23, oo = t45 + t67;
    const float A  = ee + oo;
    const float B5 = ee - oo;                                   // (-1)^{r2}
    const float B6 = (t01 - t23) + (t45 - t67);                 // (-1)^{r1}
    const float B7 = (P[0] - P[1]) + (P[2] - P[3])
                   - (P[4] - P[5]) - (P[6] - P[7]);             // (-1)^{r2^r0}

    // sign words (bit31 masks): b4, b3, b4^b2, b3^b1, b4^b2^b0
    const unsigned m_b4  = (unsigned)(sub & 16) << 27;
    const unsigned m_b3  = (unsigned)(sub & 8)  << 28;
    const unsigned m_gE  = (unsigned)(((sub >> 4) ^ (sub >> 2)) & 1) << 31;
    const unsigned m_gO  = (unsigned)(((sub >> 3) ^ (sub >> 1)) & 1) << 31;
    const unsigned m_gE0 = (unsigned)(((sub >> 4) ^ (sub >> 2) ^ sub) & 1) << 31;

    float z[8];
    z[0] = xorf(A,  m_b4);
    z[1] = xorf(A,  m_b3);
    z[2] = xorf(A,  m_gE);
    z[3] = xorf(A,  m_gO);
    z[4] = xorf(A,  m_gE0);
    z[5] = xorf(B5, m_gO);
    z[6] = xorf(B6, m_gE0);
    z[7] = xorf(B7, m_gO);

    // ---- reduce-scatter: lane (sub&7) ends holding z_{sub&7} summed over 32 lanes ----
    const bool c2 = (sub >> 2) & 1, c1 = (sub >> 1) & 1, c0 = sub & 1;
    float a4[4];
#pragma unroll
    for (int k = 0; k < 4; ++k) {
        const float keep = c2 ? z[k + 4] : z[k];
        const float send = c2 ? z[k]     : z[k + 4];
        a4[k] = keep + swz<4>(send);
    }
    float a2[2];
#pragma unroll
    for (int m = 0; m < 2; ++m) {
        const float keep = c1 ? a4[m + 2] : a4[m];
        const float send = c1 ? a4[m]     : a4[m + 2];
        a2[m] = keep + dpp1<QP_XOR2>(send);
    }
    float w;
    {
        const float keep = c0 ? a2[1] : a2[0];
        const float send = c0 ? a2[0] : a2[1];
        w = keep + dpp1<QP_XOR1>(send);
    }
    w += dpp1<ROW_ROR8>(w);   // sum over b3
    w += swz<16>(w);          // sum over b4

    if (sub < 8) out[sample * 8 + sub] = w;
}

extern "C" void kernel_launch(void* const* d_in, const int* in_sizes, int n_in,
                              void* d_out, int out_size, void* d_ws, size_t ws_size,
                              hipStream_t stream) {
    const float* x     = (const float*)d_in[0];
    const float* theta = (const float*)d_in[1];
    float* out = (float*)d_out;
    const int B = in_sizes[0] / 8;
    const long long threads_total = (long long)B * 32;   // 32 lanes per sample
    const int blocks = (int)((threads_total + 255) / 256);
    hipLaunchKernelGGL(quantum_kernel, dim3(blocks), dim3(256), 0, stream,
                       x, theta, out, B);
}